// Round 1
// baseline (375.516 us; speedup 1.0000x reference)
//
#include <hip/hip_runtime.h>

// RoIBridge: gather sinusoidal positional embeddings per bbox coordinate,
// mask by obj_vec==1, write dense [B*T, 256] fp32 buffer.
// B=2048, T=128, D=64, IMAGE_SIZE=224 (table has 225 rows).
//
// Memory-bound: 256 MiB output writes dominate. One thread per output float4.

#define ROI_B 2048
#define ROI_T 128
#define ROI_D 64
#define ROI_IMG 224.0f

__global__ __launch_bounds__(256) void RoIBridge_kernel(
    const float* __restrict__ bboxs,   // [B*T*4] fractional bboxes
    const int*   __restrict__ objs,    // [B*T]
    const float* __restrict__ table,   // [225*64] positional table
    float4*      __restrict__ out)     // [B*T*64] as float4
{
    const int g   = blockIdx.x * blockDim.x + threadIdx.x; // float4 index
    const int row = g >> 6;   // (b,t) flat index — wave-uniform (64 f4/row)
    const int f   = g & 63;   // float4 within the 256-float row
    const int c   = f >> 4;   // coord 0..3 — shared by 16 consecutive lanes
    const int d4  = f & 15;   // float4 within the 64-float embedding

    // obj mask: all 64 lanes of a wave hit the same address -> broadcast
    const bool on = (objs[row] == 1);

    // fractional coord -> clamped integer index (truncation toward 0)
    const float frac = bboxs[(row << 2) + c];
    float v = frac * ROI_IMG;
    v = fminf(fmaxf(v, 0.0f), ROI_IMG);
    const int idx = (int)v;

    // gather one float4 of the embedding row; 16 lanes read one full
    // 256B table row contiguously (L1/L2 resident: table is 57.6 KB)
    const float4 e = ((const float4*)table)[idx * (ROI_D / 4) + d4];

    const float4 z = make_float4(0.0f, 0.0f, 0.0f, 0.0f);
    out[g] = on ? e : z;
}

extern "C" void kernel_launch(void* const* d_in, const int* in_sizes, int n_in,
                              void* d_out, int out_size, void* d_ws, size_t ws_size,
                              hipStream_t stream) {
    const float* bboxs = (const float*)d_in[0];   // [2048,128,4] fp32
    const int*   objs  = (const int*)d_in[1];     // [2048,128] int32
    const float* table = (const float*)d_in[2];   // [225,64] fp32
    float4* out = (float4*)d_out;                 // [262144, 256] fp32

    const int total_f4 = (ROI_B * ROI_T * ROI_D); // 2048*128*64 = 16,777,216
    const int block = 256;
    const int grid  = total_f4 / block;           // 65,536 blocks

    RoIBridge_kernel<<<grid, block, 0, stream>>>(bboxs, objs, table, out);
}

// Round 3
// 272.997 us; speedup vs baseline: 1.3755x; 1.3755x over previous
//
#include <hip/hip_runtime.h>

// RoIBridge: gather sinusoidal positional embeddings per bbox coordinate,
// mask by obj_vec==1, write dense [B*T, 256] fp32 buffer.
// B=2048, T=128, D=64, IMAGE_SIZE=224 (table: 225x64 fp32 = 57.6 KB).
//
// Memory-bound: 268 MB output stream dominates. Design:
//  - wave (64 lanes) covers one 256-float row; 4 rows per wave
//    => 4 independent load->gather->store chains for ILP.
//  - nontemporal stores keep the write-once output out of L2 so the
//    57.6 KB table stays cache-resident for the gathers.
//  - lanes 0-15 share one bbox coord (broadcast); each 16-lane group reads
//    one contiguous 256 B table row; stores fully coalesced 16 B/lane.

#define ROI_ROWS (2048 * 128)   // B*T = 262,144
#define ROI_IMG  224.0f
#define ROWS_PER_WAVE 4

// native vector type: __builtin_nontemporal_store needs this, not HIP float4
typedef float vfloat4 __attribute__((ext_vector_type(4)));

__global__ __launch_bounds__(256) void RoIBridge_kernel(
    const float*   __restrict__ bboxs,   // [ROWS*4]
    const int*     __restrict__ objs,    // [ROWS]
    const vfloat4* __restrict__ table,   // [225*16] float4s
    vfloat4*       __restrict__ out)     // [ROWS*64] float4s
{
    const int tid  = blockIdx.x * 256 + threadIdx.x;
    const int wave = tid >> 6;
    const int lane = threadIdx.x & 63;
    const int c    = lane >> 4;        // coord 0..3 (16 lanes each)
    const int d4   = lane & 15;        // float4 within 64-float embedding

    const int row0 = wave * ROWS_PER_WAVE;

    // Phase 1: independent input loads up front
    int   obj[ROWS_PER_WAVE];
    float frac[ROWS_PER_WAVE];
#pragma unroll
    for (int r = 0; r < ROWS_PER_WAVE; ++r) {
        obj[r]  = objs[row0 + r];
        frac[r] = bboxs[((row0 + r) << 2) + c];
    }

    // Phase 2: dependent gathers (4 independent chains in flight)
    vfloat4 e[ROWS_PER_WAVE];
#pragma unroll
    for (int r = 0; r < ROWS_PER_WAVE; ++r) {
        float v = fminf(fmaxf(frac[r] * ROI_IMG, 0.0f), ROI_IMG);
        const int idx = (int)v;            // trunc toward 0
        e[r] = table[idx * 16 + d4];       // 256B/row, coalesced
    }

    // Phase 3: masked streaming stores (bypass L2)
    const vfloat4 z = (vfloat4){0.0f, 0.0f, 0.0f, 0.0f};
#pragma unroll
    for (int r = 0; r < ROWS_PER_WAVE; ++r) {
        const vfloat4 val = (obj[r] == 1) ? e[r] : z;
        __builtin_nontemporal_store(val, &out[(row0 + r) * 64 + lane]);
    }
}

extern "C" void kernel_launch(void* const* d_in, const int* in_sizes, int n_in,
                              void* d_out, int out_size, void* d_ws, size_t ws_size,
                              hipStream_t stream) {
    const float*   bboxs = (const float*)d_in[0];   // [2048,128,4] fp32
    const int*     objs  = (const int*)d_in[1];     // [2048,128] int32
    const vfloat4* table = (const vfloat4*)d_in[2]; // [225,64] fp32
    vfloat4* out = (vfloat4*)d_out;                 // [262144*64] float4

    // waves = ROWS/4 = 65,536 ; blocks (4 waves each) = 16,384
    RoIBridge_kernel<<<ROI_ROWS / (ROWS_PER_WAVE * 4), 256, 0, stream>>>(
        bboxs, objs, table, out);
}